// Round 1
// baseline (89.714 us; speedup 1.0000x reference)
//
#include <hip/hip_runtime.h>

// Problem constants
#define RES    128
#define P_PTS  4096
#define CHUNKS 16

typedef _Float16 half8  __attribute__((ext_vector_type(8)));
typedef _Float16 half2v __attribute__((ext_vector_type(2)));
typedef float    f32x4  __attribute__((ext_vector_type(4)));

// Workspace layout (bytes):
//   part : 16 chunks * 131072 half2          = 8 MB  @ 0
//   Ax   : 1024 g * 128 n * half8 (16 B)     = 2 MB  @ 8 MB
//          Ax[g][n] = e^{i 2pi tx_p (n-64)/128}, p = 4g..4g+3 interleaved (re,im)x4
//   Ayc  : 8 b * 1024 g * 128 m * half8      = 16 MB @ 10 MB
//          Ayc[b][g][m] = (c[b,p]/128) * e^{i 2pi ty_p (m-64)/128}
#define AX_OFF   8388608
#define AYC_OFF 10485760

// ---------------------------------------------------------------------------
// prep: grid (32 gc, 9 bb) x 256 thr. Each block covers 128 trajectory points
// (g in [gc*32, gc*32+32)). bb==8 -> Ax slice; bb<8 -> c-folded Ayc slice for
// batch bb (grid-sample + fold in f32, round to f16 once — same numerics as
// the previous passing kernel).
// ---------------------------------------------------------------------------
__global__ __launch_bounds__(256) void prep_kernel(const float* __restrict__ ksp,
                                                   const float* __restrict__ traj,
                                                   half8* __restrict__ Ax_t,
                                                   half8* __restrict__ Ayc_t) {
    __shared__ float2 st[128];   // (tx, ty)
    __shared__ float2 sc[128];   // c[b,p]/128
    const int gc  = blockIdx.x;  // 0..31
    const int bb  = blockIdx.y;  // 0..8 (8 == Ax)
    const int tid = threadIdx.x;

    if (tid < 128) {
        const int p = gc * 128 + tid;
        const float tx = traj[2 * p], ty = traj[2 * p + 1];
        st[tid] = make_float2(tx, ty);
        if (bb < 8) {
            // bilinear grid-sample (zero padding, align_corners=False)
            const float x = tx + 63.5f, y = ty + 63.5f;
            const float x0f = floorf(x), y0f = floorf(y);
            const float wx = x - x0f, wy = y - y0f;
            const int ix0 = (int)x0f, iy0 = (int)y0f;
            float re = 0.0f, im = 0.0f;
#pragma unroll
            for (int dy = 0; dy < 2; ++dy) {
#pragma unroll
                for (int dx = 0; dx < 2; ++dx) {
                    const int ix = ix0 + dx, iy = iy0 + dy;
                    const float w = (dx ? wx : 1.0f - wx) * (dy ? wy : 1.0f - wy);
                    if (ix >= 0 && ix < RES && iy >= 0 && iy < RES) {
                        const float2 v = *(const float2*)(ksp + ((bb * RES + iy) * RES + ix) * 2);
                        re = fmaf(v.x, w, re);
                        im = fmaf(v.y, w, im);
                    }
                }
            }
            sc[tid] = make_float2(re * (1.0f / 128.0f), im * (1.0f / 128.0f));
        }
    }
    __syncthreads();

    const float inv = 1.0f / 128.0f;
#pragma unroll
    for (int k = 0; k < 16; ++k) {
        const int e   = k * 256 + tid;   // 0..4095
        const int gl  = e >> 7;          // local g 0..31
        const int col = e & 127;         // n (Ax) or m (Ayc)
        const float xc = ((float)col - 64.0f) * inv;
        half8 v;
        if (bb == 8) {
#pragma unroll
            for (int j = 0; j < 4; ++j) {
                const int pl = gl * 4 + j;
                const float rev = st[pl].x * xc;
                const float f = rev - floorf(rev);
                v[2 * j]     = (_Float16)__builtin_amdgcn_cosf(f);
                v[2 * j + 1] = (_Float16)__builtin_amdgcn_sinf(f);
            }
            Ax_t[(size_t)(gc * 32 + gl) * 128 + col] = v;
        } else {
#pragma unroll
            for (int j = 0; j < 4; ++j) {
                const int pl = gl * 4 + j;
                const float rev = st[pl].y * xc;
                const float f = rev - floorf(rev);
                const float cs = __builtin_amdgcn_cosf(f);
                const float sn = __builtin_amdgcn_sinf(f);
                const float cr = sc[pl].x, ci = sc[pl].y;
                v[2 * j]     = (_Float16)(cr * cs - ci * sn);
                v[2 * j + 1] = (_Float16)(cr * sn + ci * cs);
            }
            Ayc_t[((size_t)bb * 1024 + gc * 32 + gl) * 128 + col] = v;
        }
    }
}

// ---------------------------------------------------------------------------
// gemm: grid (16 chunk, 16 = b*2+mh, 2 nh) x 256 thr = 512 blocks (2/CU).
// Barrier-free, LDS-free: each MFMA fragment is a direct coalesced 16 B load
// from the L1/L2-resident tables. Wave tile M64 x N16, 4x(R+I) mfma per
// 16-point k-step, 16 k-steps (256 p per chunk). Complex mul via sign/shuffle
// on the single B fragment: Re = a.(br,-bi), Im = a.(bi,br).
// ---------------------------------------------------------------------------
__global__ __launch_bounds__(256, 2) void gemm_kernel(const half8* __restrict__ Ax_t,
                                                      const half8* __restrict__ Ayc_t,
                                                      half2v* __restrict__ part) {
    const int chunk = blockIdx.x;           // 0..15
    const int b     = blockIdx.y >> 1;      // 0..7
    const int mh    = blockIdx.y & 1;       // 0..1
    const int nh    = blockIdx.z;           // 0..1
    const int tid   = threadIdx.x;
    const int wave  = tid >> 6;
    const int lane  = tid & 63;
    const int l15   = lane & 15;
    const int q     = lane >> 4;

    const int ncol = nh * 64 + wave * 16 + l15;
    const half8* bp = Ax_t  + (size_t)(chunk * 64 + q) * 128 + ncol;
    const half8* ap = Ayc_t + ((size_t)b * 1024 + chunk * 64 + q) * 128 + mh * 64 + l15;

    f32x4 accR[4], accI[4];
#pragma unroll
    for (int i = 0; i < 4; ++i) {
        accR[i] = (f32x4){0.f, 0.f, 0.f, 0.f};
        accI[i] = (f32x4){0.f, 0.f, 0.f, 0.f};
    }

    const half8 SGN = {(_Float16)1.f, (_Float16)-1.f, (_Float16)1.f, (_Float16)-1.f,
                       (_Float16)1.f, (_Float16)-1.f, (_Float16)1.f, (_Float16)-1.f};

#pragma unroll 4
    for (int ks = 0; ks < 16; ++ks) {
        const half8 bv = bp[(size_t)ks * 512];                      // 4g x 128n stride
        const half8 b1 = bv * SGN;                                  // (br, -bi)
        const half8 b2 = __builtin_shufflevector(bv, bv,
                                                 1, 0, 3, 2, 5, 4, 7, 6);  // (bi, br)
        half8 an[4];
#pragma unroll
        for (int mt = 0; mt < 4; ++mt)
            an[mt] = ap[(size_t)ks * 512 + mt * 16];
#pragma unroll
        for (int mt = 0; mt < 4; ++mt) {
            accR[mt] = __builtin_amdgcn_mfma_f32_16x16x32_f16(an[mt], b1, accR[mt], 0, 0, 0);
            accI[mt] = __builtin_amdgcn_mfma_f32_16x16x32_f16(an[mt], b2, accI[mt], 0, 0, 0);
        }
    }

    // epilogue: C/D layout col=lane&15 (n side), row=q*4+reg (m side)
#pragma unroll
    for (int mt = 0; mt < 4; ++mt) {
#pragma unroll
        for (int rg = 0; rg < 4; ++rg) {
            const int m = b * 128 + mh * 64 + mt * 16 + q * 4 + rg;
            half2v pv;
            pv[0] = (_Float16)accR[mt][rg];
            pv[1] = (_Float16)accI[mt][rg];
            part[(size_t)chunk * 131072 + m * 128 + ncol] = pv;
        }
    }
}

// ---------------------------------------------------------------------------
// reduce: sum 16 fp16 partials in fp32 -> out (B,1,128,128,2) fp32.
// Vectorized: one half8 (4 half2) per thread, dwordx4 in / 2x dwordx4 out.
// ---------------------------------------------------------------------------
__global__ __launch_bounds__(256) void reduce_kernel(const half8* __restrict__ part,
                                                     f32x4* __restrict__ out) {
    const int i = blockIdx.x * 256 + threadIdx.x;   // 0..32767
    float s[8];
#pragma unroll
    for (int k = 0; k < 8; ++k) s[k] = 0.f;
#pragma unroll
    for (int c = 0; c < CHUNKS; ++c) {
        const half8 v = part[(size_t)c * 32768 + i];
#pragma unroll
        for (int k = 0; k < 8; ++k) s[k] += (float)v[k];
    }
    f32x4 lo = {s[0], s[1], s[2], s[3]};
    f32x4 hi = {s[4], s[5], s[6], s[7]};
    out[2 * i]     = lo;
    out[2 * i + 1] = hi;
}

// ---------------------------------------------------------------------------
extern "C" void kernel_launch(void* const* d_in, const int* in_sizes, int n_in,
                              void* d_out, int out_size, void* d_ws, size_t ws_size,
                              hipStream_t stream) {
    const float* ksp  = (const float*)d_in[0];   // (B,1,128,128,2) fp32
    const float* traj = (const float*)d_in[1];   // (4096,2) fp32
    half2v* part = (half2v*)d_ws;
    half8*  Ax   = (half8*)((char*)d_ws + AX_OFF);
    half8*  Ayc  = (half8*)((char*)d_ws + AYC_OFF);

    hipLaunchKernelGGL(prep_kernel,   dim3(32, 9),     dim3(256), 0, stream,
                       ksp, traj, Ax, Ayc);
    hipLaunchKernelGGL(gemm_kernel,   dim3(CHUNKS, 16, 2), dim3(256), 0, stream,
                       Ax, Ayc, part);
    hipLaunchKernelGGL(reduce_kernel, dim3(128),       dim3(256), 0, stream,
                       (const half8*)d_ws, (f32x4*)d_out);
}

// Round 3
// 74.984 us; speedup vs baseline: 1.1964x; 1.1964x over previous
//
#include <hip/hip_runtime.h>

// Problem constants
#define RES    128
#define P_PTS  4096
#define CHUNKS 32
#define PP     128          // trajectory points per chunk

// Workspace: part half2 [32][1024*128] = 16 MB at offset 0
typedef _Float16 half8  __attribute__((ext_vector_type(8)));
typedef _Float16 half2v __attribute__((ext_vector_type(2)));
typedef float    f32x4  __attribute__((ext_vector_type(4)));

// ---------------------------------------------------------------------------
// fused gemm: grid (32 chunks, 16 = b*2+mh). 256 thr = 4 waves.
// 2 blocks/CU (2 waves/SIMD) so barrier/trans/LDS latency of one block is
// hidden by the other. Per block: cache traj + grid-sampled c for its 128 p's
// in LDS, then 4 rounds of {generate sA/sB tiles via v_sin/v_cos, MFMA}.
// Block tile M64 x N128, wave tile M64 x N32, complex mul via sign/shuffle on
// the 2 B fragments (Re = a.(br,-bi), Im = a.(bi,br)).
// ---------------------------------------------------------------------------
__global__ __launch_bounds__(256) void gemm_kernel(const float* __restrict__ ksp,
                                                   const float* __restrict__ traj,
                                                   half2v* __restrict__ part) {
    __shared__ float2 st[PP];                       // (tx, ty) per p
    __shared__ float2 sc[PP];                       // c[b,p]/128
    __shared__ __align__(16) _Float16 sA[4096];     // [k8l(8)][m(64)][8]
    __shared__ __align__(16) _Float16 sB[8192];     // [k8l(8)][n(128)][8]

    const int chunk = blockIdx.x;          // 0..31
    const int b     = blockIdx.y >> 1;     // 0..7
    const int mh    = blockIdx.y & 1;      // 0..1
    const int tid   = threadIdx.x;
    const int wave  = tid >> 6;
    const int lane  = tid & 63;
    const int l15   = lane & 15;
    const int q     = lane >> 4;

    // ---- setup: traj slice + bilinear grid-sample (one p per thread) ----
    if (tid < PP) {
        const int p = chunk * PP + tid;
        const float tx = traj[2 * p], ty = traj[2 * p + 1];
        st[tid] = make_float2(tx, ty);
        const float x = tx + 63.5f, y = ty + 63.5f;
        const float x0f = floorf(x), y0f = floorf(y);
        const float wx = x - x0f, wy = y - y0f;
        const int ix0 = (int)x0f, iy0 = (int)y0f;
        float re = 0.0f, im = 0.0f;
#pragma unroll
        for (int dy = 0; dy < 2; ++dy) {
#pragma unroll
            for (int dx = 0; dx < 2; ++dx) {
                const int ix = ix0 + dx, iy = iy0 + dy;
                const float w = (dx ? wx : 1.0f - wx) * (dy ? wy : 1.0f - wy);
                if (ix >= 0 && ix < RES && iy >= 0 && iy < RES) {
                    const float2 v = *(const float2*)(ksp + ((b * RES + iy) * RES + ix) * 2);
                    re = fmaf(v.x, w, re);
                    im = fmaf(v.y, w, im);
                }
            }
        }
        sc[tid] = make_float2(re * (1.0f / 128.0f), im * (1.0f / 128.0f));
    }
    __syncthreads();

    f32x4 accR[4][2], accI[4][2];
#pragma unroll
    for (int i = 0; i < 4; ++i)
#pragma unroll
        for (int j = 0; j < 2; ++j) {
            accR[i][j] = (f32x4){0.f, 0.f, 0.f, 0.f};
            accI[i][j] = (f32x4){0.f, 0.f, 0.f, 0.f};
        }

    const float inv = 1.0f / 128.0f;
    const int nB = tid & 127, kB = tid >> 7;    // B-gen: k8l = kB + 2i (wave-uniform)
    const int mA = tid & 63,  kA = tid >> 6;    // A-gen: k8l = kA + 4i (wave-uniform)
    const float xn = ((float)nB - 64.0f) * inv;
    const float xm = ((float)(mh * 64 + mA) - 64.0f) * inv;

    for (int r = 0; r < 4; ++r) {               // PP/32 rounds
        const int p0 = r * 32;
        // ---- generate B tile: Ax phasors ----
#pragma unroll
        for (int i = 0; i < 4; ++i) {
            const int k8l = kB + 2 * i;
            half8 v;
#pragma unroll
            for (int j = 0; j < 4; ++j) {
                const int pl = p0 + k8l * 4 + j;       // LDS broadcast (wave-uniform)
                const float rev = st[pl].x * xn;
                const float f = rev - floorf(rev);
                v[2 * j]     = (_Float16)__builtin_amdgcn_cosf(f);
                v[2 * j + 1] = (_Float16)__builtin_amdgcn_sinf(f);
            }
            *(half8*)(sB + ((size_t)(k8l * 128 + nB)) * 8) = v;
        }
        // ---- generate A tile: c-folded Ay phasors ----
#pragma unroll
        for (int i = 0; i < 2; ++i) {
            const int k8l = kA + 4 * i;
            half8 v;
#pragma unroll
            for (int j = 0; j < 4; ++j) {
                const int pl = p0 + k8l * 4 + j;
                const float rev = st[pl].y * xm;
                const float f = rev - floorf(rev);
                const float cs = __builtin_amdgcn_cosf(f);
                const float sn = __builtin_amdgcn_sinf(f);
                const float cr = sc[pl].x, ci = sc[pl].y;
                v[2 * j]     = (_Float16)(cr * cs - ci * sn);
                v[2 * j + 1] = (_Float16)(cr * sn + ci * cs);
            }
            *(half8*)(sA + ((size_t)(k8l * 64 + mA)) * 8) = v;
        }
        __syncthreads();

        // ---- MFMA on the tile ----
        const half8 SGN = {(_Float16)1.f, (_Float16)-1.f, (_Float16)1.f, (_Float16)-1.f,
                           (_Float16)1.f, (_Float16)-1.f, (_Float16)1.f, (_Float16)-1.f};
#pragma unroll
        for (int s = 0; s < 2; ++s) {
            const _Float16* pa = sA + (s * 4 + q) * 512;
            const _Float16* pb = sB + (s * 4 + q) * 1024;
            half8 an[4], b1[2], b2[2];
#pragma unroll
            for (int mt = 0; mt < 4; ++mt)
                an[mt] = *(const half8*)(pa + (mt * 16 + l15) * 8);
#pragma unroll
            for (int nt = 0; nt < 2; ++nt) {
                const half8 bv = *(const half8*)(pb + (wave * 32 + nt * 16 + l15) * 8);
                b1[nt] = bv * SGN;                                     // (br,-bi)
                b2[nt] = __builtin_shufflevector(bv, bv,
                                                 1, 0, 3, 2, 5, 4, 7, 6); // (bi,br)
            }
#pragma unroll
            for (int mt = 0; mt < 4; ++mt)
#pragma unroll
                for (int nt = 0; nt < 2; ++nt) {
                    accR[mt][nt] = __builtin_amdgcn_mfma_f32_16x16x32_f16(
                        an[mt], b1[nt], accR[mt][nt], 0, 0, 0);
                    accI[mt][nt] = __builtin_amdgcn_mfma_f32_16x16x32_f16(
                        an[mt], b2[nt], accI[mt][nt], 0, 0, 0);
                }
        }
        __syncthreads();
    }

    // ---- epilogue: C/D layout col=lane&15, row=q*4+reg ----
#pragma unroll
    for (int mt = 0; mt < 4; ++mt) {
#pragma unroll
        for (int nt = 0; nt < 2; ++nt) {
            const int n = wave * 32 + nt * 16 + l15;
#pragma unroll
            for (int rg = 0; rg < 4; ++rg) {
                const int m = b * 128 + mh * 64 + mt * 16 + q * 4 + rg;
                half2v pv;
                pv[0] = (_Float16)accR[mt][nt][rg];
                pv[1] = (_Float16)accI[mt][nt][rg];
                part[(size_t)chunk * 131072 + m * 128 + n] = pv;
            }
        }
    }
}

// ---------------------------------------------------------------------------
// reduce: sum 32 fp16 partials in fp32 -> out (B,1,128,128,2) fp32.
// Vectorized: one half8 (4 half2) per thread, dwordx4 in / 2x dwordx4 out.
// ---------------------------------------------------------------------------
__global__ __launch_bounds__(256) void reduce_kernel(const half8* __restrict__ part,
                                                     f32x4* __restrict__ out) {
    const int i = blockIdx.x * 256 + threadIdx.x;   // 0..32767
    float s[8];
#pragma unroll
    for (int k = 0; k < 8; ++k) s[k] = 0.f;
#pragma unroll
    for (int c = 0; c < CHUNKS; ++c) {
        const half8 v = part[(size_t)c * 32768 + i];
#pragma unroll
        for (int k = 0; k < 8; ++k) s[k] += (float)v[k];
    }
    f32x4 lo = {s[0], s[1], s[2], s[3]};
    f32x4 hi = {s[4], s[5], s[6], s[7]};
    out[2 * i]     = lo;
    out[2 * i + 1] = hi;
}

// ---------------------------------------------------------------------------
extern "C" void kernel_launch(void* const* d_in, const int* in_sizes, int n_in,
                              void* d_out, int out_size, void* d_ws, size_t ws_size,
                              hipStream_t stream) {
    const float* ksp  = (const float*)d_in[0];   // (B,1,128,128,2) fp32
    const float* traj = (const float*)d_in[1];   // (4096,2) fp32
    half2v* part = (half2v*)d_ws;

    hipLaunchKernelGGL(gemm_kernel,   dim3(CHUNKS, 16), dim3(256), 0, stream,
                       ksp, traj, part);
    hipLaunchKernelGGL(reduce_kernel, dim3(128),        dim3(256), 0, stream,
                       (const half8*)part, (f32x4*)d_out);
}